// Round 1
// baseline (521.069 us; speedup 1.0000x reference)
//
#include <hip/hip_runtime.h>
#include <math.h>

#define N_NODES 10000
#define N_EDGES 50000
#define IN_F    1433
#define OUT_F   256
#define FCHUNKS 6   // ceil(1433/256)

// ---------------- CSR build ----------------

__global__ void k_zero(int* __restrict__ counts, int n) {
    int i = blockIdx.x * blockDim.x + threadIdx.x;
    if (i < n) counts[i] = 0;
}

__global__ void k_hist(const int* __restrict__ edges, int* __restrict__ counts) {
    int e = blockIdx.x * blockDim.x + threadIdx.x;
    if (e < N_EDGES) {
        int dst = edges[2 * e];
        int src = edges[2 * e + 1];
        if (src < N_NODES) atomicAdd(&counts[dst], 1);
    }
}

// Single-block exclusive scan over N_NODES counts -> offsets[0..N_NODES]
__global__ void __launch_bounds__(1024) k_scan(const int* __restrict__ counts,
                                               int* __restrict__ offsets) {
    __shared__ int buf[1024];
    __shared__ int carry_s;
    if (threadIdx.x == 0) carry_s = 0;
    __syncthreads();
    for (int base = 0; base < N_NODES; base += 1024) {
        int i = base + (int)threadIdx.x;
        int v = (i < N_NODES) ? counts[i] : 0;
        buf[threadIdx.x] = v;
        __syncthreads();
        for (int off = 1; off < 1024; off <<= 1) {
            int t = (threadIdx.x >= (unsigned)off) ? buf[threadIdx.x - off] : 0;
            __syncthreads();
            buf[threadIdx.x] += t;
            __syncthreads();
        }
        int incl = buf[threadIdx.x];
        int carry = carry_s;
        if (i < N_NODES) offsets[i] = carry + incl - v;  // exclusive
        __syncthreads();
        if (threadIdx.x == 1023) carry_s = carry + buf[1023];
        __syncthreads();
    }
    if (threadIdx.x == 0) offsets[N_NODES] = carry_s;
}

__global__ void k_copy(const int* __restrict__ src, int* __restrict__ dstp, int n) {
    int i = blockIdx.x * blockDim.x + threadIdx.x;
    if (i < n) dstp[i] = src[i];
}

__global__ void k_fill(const int* __restrict__ edges, int* __restrict__ cursor,
                       int* __restrict__ edge_src) {
    int e = blockIdx.x * blockDim.x + threadIdx.x;
    if (e < N_EDGES) {
        int dst = edges[2 * e];
        int src = edges[2 * e + 1];
        if (src < N_NODES) {
            int pos = atomicAdd(&cursor[dst], 1);
            edge_src[pos] = src;
        }
    }
}

// ---------------- aggregate + fused row-norm ----------------
// one block (256 thr) per node: agg[i] = noise[i] + sum_{e:dst=i} feat[src_e]
// rnorm[i] = 1 / max(||agg[i]||_2, 1e-12)

__global__ void __launch_bounds__(256) k_agg(const float* __restrict__ feat,
                                             const float* __restrict__ noise,
                                             const int* __restrict__ offsets,
                                             const int* __restrict__ edge_src,
                                             float* __restrict__ agg,
                                             float* __restrict__ rnorm) {
    __shared__ int nb[256];
    __shared__ float warp_s[4];
    const int node = blockIdx.x;
    const int t = threadIdx.x;
    const int beg = offsets[node];
    const int end = offsets[node + 1];

    float acc[FCHUNKS];
#pragma unroll
    for (int j = 0; j < FCHUNKS; ++j) {
        int f = t + j * 256;
        acc[j] = (f < IN_F) ? noise[(size_t)node * IN_F + f] : 0.0f;
    }

    for (int cb = beg; cb < end; cb += 256) {
        int cnt = min(256, end - cb);
        __syncthreads();
        if (t < cnt) nb[t] = edge_src[cb + t];
        __syncthreads();
        for (int k = 0; k < cnt; ++k) {
            const float* row = feat + (size_t)nb[k] * IN_F;
#pragma unroll
            for (int j = 0; j < FCHUNKS; ++j) {
                int f = t + j * 256;
                if (f < IN_F) acc[j] += row[f];
            }
        }
    }

    float sumsq = 0.0f;
#pragma unroll
    for (int j = 0; j < FCHUNKS; ++j) {
        int f = t + j * 256;
        if (f < IN_F) {
            agg[(size_t)node * IN_F + f] = acc[j];
            sumsq += acc[j] * acc[j];
        }
    }
    // block reduce (wave=64)
    for (int off = 32; off > 0; off >>= 1) sumsq += __shfl_down(sumsq, off, 64);
    if ((t & 63) == 0) warp_s[t >> 6] = sumsq;
    __syncthreads();
    if (t == 0) {
        float tot = warp_s[0] + warp_s[1] + warp_s[2] + warp_s[3];
        rnorm[node] = 1.0f / fmaxf(sqrtf(tot), 1e-12f);
    }
}

// ---------------- fp32 GEMM: out = (agg @ W) * rnorm[row] + bias ----------------
// BM=64 BN=64 BK=16, 256 threads = 16x16, 4x4 acc per thread

#define BM 64
#define BN 64
#define BK 16

__global__ void __launch_bounds__(256) k_gemm(const float* __restrict__ A,
                                              const float* __restrict__ W,
                                              const float* __restrict__ bias,
                                              const float* __restrict__ rnorm,
                                              float* __restrict__ out) {
    __shared__ float As[BK][BM + 1];  // +1 pad: transposed store, conflict-free
    __shared__ float Bs[BK][BN];

    const int tid = threadIdx.x;
    const int tx = tid & 15;   // N dir
    const int ty = tid >> 4;   // M dir
    const int row0 = blockIdx.y * BM;
    const int col0 = blockIdx.x * BN;

    float acc[4][4] = {};

    for (int k0 = 0; k0 < IN_F; k0 += BK) {
        // A tile: 64 rows x 16 k (transposed into As[k][m])
#pragma unroll
        for (int i = 0; i < 4; ++i) {
            int r = (tid >> 4) + i * 16;
            int c = tid & 15;
            int gr = row0 + r, gc = k0 + c;
            As[c][r] = (gr < N_NODES && gc < IN_F) ? A[(size_t)gr * IN_F + gc] : 0.0f;
        }
        // B tile: 16 k x 64 n
#pragma unroll
        for (int i = 0; i < 4; ++i) {
            int kk = (tid >> 6) + i * 4;
            int nn = tid & 63;
            int gk = k0 + kk;
            Bs[kk][nn] = (gk < IN_F) ? W[(size_t)gk * OUT_F + col0 + nn] : 0.0f;
        }
        __syncthreads();
#pragma unroll
        for (int kk = 0; kk < BK; ++kk) {
            float a[4], b[4];
#pragma unroll
            for (int i = 0; i < 4; ++i) a[i] = As[kk][ty * 4 + i];
#pragma unroll
            for (int j = 0; j < 4; ++j) b[j] = Bs[kk][tx * 4 + j];
#pragma unroll
            for (int i = 0; i < 4; ++i)
#pragma unroll
                for (int j = 0; j < 4; ++j) acc[i][j] += a[i] * b[j];
        }
        __syncthreads();
    }

#pragma unroll
    for (int i = 0; i < 4; ++i) {
        int gr = row0 + ty * 4 + i;
        if (gr < N_NODES) {
            float rn = rnorm[gr];
#pragma unroll
            for (int j = 0; j < 4; ++j) {
                int gc = col0 + tx * 4 + j;
                out[(size_t)gr * OUT_F + gc] = acc[i][j] * rn + bias[gc];
            }
        }
    }
}

// ---------------- launch ----------------

extern "C" void kernel_launch(void* const* d_in, const int* in_sizes, int n_in,
                              void* d_out, int out_size, void* d_ws, size_t ws_size,
                              hipStream_t stream) {
    const float* feat  = (const float*)d_in[0];  // 10000 x 1433
    const int*   edges = (const int*)d_in[1];    // 50000 x 2 (dst, src)
    const float* W     = (const float*)d_in[2];  // 1433 x 256
    const float* bias  = (const float*)d_in[3];  // 256
    const float* noise = (const float*)d_in[4];  // 10000 x 1433
    float* out = (float*)d_out;                  // 10000 x 256

    // workspace carve-up
    char* ws = (char*)d_ws;
    size_t off = 0;
    auto carve = [&](size_t bytes) {
        void* p = ws + off;
        off = (off + bytes + 255) & ~(size_t)255;
        return p;
    };
    float* agg      = (float*)carve((size_t)N_NODES * IN_F * sizeof(float));
    float* rnorm    = (float*)carve((size_t)N_NODES * sizeof(float));
    int*   counts   = (int*)carve((size_t)(N_NODES + 1) * sizeof(int));
    int*   offsets  = (int*)carve((size_t)(N_NODES + 1) * sizeof(int));
    int*   cursor   = (int*)carve((size_t)(N_NODES + 1) * sizeof(int));
    int*   edge_src = (int*)carve((size_t)N_EDGES * sizeof(int));
    (void)ws_size;

    const int TB = 256;
    k_zero<<<(N_NODES + 1 + TB - 1) / TB, TB, 0, stream>>>(counts, N_NODES + 1);
    k_hist<<<(N_EDGES + TB - 1) / TB, TB, 0, stream>>>(edges, counts);
    k_scan<<<1, 1024, 0, stream>>>(counts, offsets);
    k_copy<<<(N_NODES + TB - 1) / TB, TB, 0, stream>>>(offsets, cursor, N_NODES);
    k_fill<<<(N_EDGES + TB - 1) / TB, TB, 0, stream>>>(edges, cursor, edge_src);
    k_agg<<<N_NODES, 256, 0, stream>>>(feat, noise, offsets, edge_src, agg, rnorm);
    dim3 ggrid(OUT_F / BN, (N_NODES + BM - 1) / BM);
    k_gemm<<<ggrid, 256, 0, stream>>>(agg, W, bias, rnorm, out);
}

// Round 2
// 298.354 us; speedup vs baseline: 1.7465x; 1.7465x over previous
//
#include <hip/hip_runtime.h>
#include <math.h>

#define N_NODES 10000
#define N_EDGES 50000
#define IN_F    1433
#define OUT_F   256

// padded GEMM dims: M = [X(10000); noise(10000); zeros(96)] = 20096 = 157*128
//                   K = 1440 = 45*32 (zero-padded cols 1433..1439)
#define GM 20096
#define GK 1440
#define NCHUNK 180   // GK/8

typedef __bf16 bf16x8 __attribute__((ext_vector_type(8)));
typedef float  f32x4  __attribute__((ext_vector_type(4)));

typedef __attribute__((address_space(3))) unsigned int lds_u32;
typedef __attribute__((address_space(1))) unsigned int glb_u32;

__device__ __forceinline__ void stage16(const void* g, void* l) {
    __builtin_amdgcn_global_load_lds((glb_u32*)g, (lds_u32*)l, 16, 0, 0);
}

// ---------------- CSR build ----------------

__global__ void k_zero(int* __restrict__ counts, int n) {
    int i = blockIdx.x * blockDim.x + threadIdx.x;
    if (i < n) counts[i] = 0;
}

__global__ void k_hist(const int* __restrict__ edges, int* __restrict__ counts) {
    int e = blockIdx.x * blockDim.x + threadIdx.x;
    if (e < N_EDGES) {
        int dst = edges[2 * e];
        int src = edges[2 * e + 1];
        if (src < N_NODES) atomicAdd(&counts[dst], 1);
    }
}

__global__ void __launch_bounds__(1024) k_scan(const int* __restrict__ counts,
                                               int* __restrict__ offsets) {
    __shared__ int buf[1024];
    __shared__ int carry_s;
    if (threadIdx.x == 0) carry_s = 0;
    __syncthreads();
    for (int base = 0; base < N_NODES; base += 1024) {
        int i = base + (int)threadIdx.x;
        int v = (i < N_NODES) ? counts[i] : 0;
        buf[threadIdx.x] = v;
        __syncthreads();
        for (int off = 1; off < 1024; off <<= 1) {
            int t = (threadIdx.x >= (unsigned)off) ? buf[threadIdx.x - off] : 0;
            __syncthreads();
            buf[threadIdx.x] += t;
            __syncthreads();
        }
        int incl = buf[threadIdx.x];
        int carry = carry_s;
        if (i < N_NODES) offsets[i] = carry + incl - v;
        __syncthreads();
        if (threadIdx.x == 1023) carry_s = carry + buf[1023];
        __syncthreads();
    }
    if (threadIdx.x == 0) offsets[N_NODES] = carry_s;
}

__global__ void k_copy(const int* __restrict__ src, int* __restrict__ dstp, int n) {
    int i = blockIdx.x * blockDim.x + threadIdx.x;
    if (i < n) dstp[i] = src[i];
}

__global__ void k_fill(const int* __restrict__ edges, int* __restrict__ cursor,
                       int* __restrict__ edge_src) {
    int e = blockIdx.x * blockDim.x + threadIdx.x;
    if (e < N_EDGES) {
        int dst = edges[2 * e];
        int src = edges[2 * e + 1];
        if (src < N_NODES) {
            int pos = atomicAdd(&cursor[dst], 1);
            edge_src[pos] = src;
        }
    }
}

// ---------------- fp32 -> bf16 convert (stacked, padded) ----------------
// Abf[row][k], row<10000: X, 10000<=row<20000: noise, else 0; k>=1433 -> 0

__global__ void k_convA(const float* __restrict__ X, const float* __restrict__ noise,
                        __bf16* __restrict__ Abf) {
    int cid = blockIdx.x * blockDim.x + threadIdx.x;   // chunk of 8
    if (cid >= GM * NCHUNK) return;
    int row = cid / NCHUNK;
    int k = (cid % NCHUNK) * 8;
    const float* src = nullptr;
    int srow = row;
    if (row < 10000) src = X;
    else if (row < 20000) { src = noise; srow = row - 10000; }
    bf16x8 v;
#pragma unroll
    for (int j = 0; j < 8; ++j) {
        int kk = k + j;
        float x = (src && kk < IN_F) ? src[(size_t)srow * IN_F + kk] : 0.0f;
        v[j] = (__bf16)x;
    }
    *(bf16x8*)(Abf + (size_t)row * GK + k) = v;
}

// WbfT[n][k] = W[k][n] (bf16, K zero-padded)
__global__ void k_convW(const float* __restrict__ W, __bf16* __restrict__ BT) {
    int i = blockIdx.x * blockDim.x + threadIdx.x;
    if (i >= OUT_F * GK) return;
    int n = i / GK, k = i % GK;
    float x = (k < IN_F) ? W[(size_t)k * OUT_F + n] : 0.0f;
    BT[i] = (__bf16)x;
}

// ---------------- bf16 MFMA GEMM: P[GM][256] = Abf @ WbfT^T ----------------
// 128x128 tile, BK=32, 256 thr = 4 waves, each wave 64x64 (4x4 of 16x16x32)

#define BK 32

__global__ void __launch_bounds__(256) k_mfma_gemm(const __bf16* __restrict__ A,
                                                   const __bf16* __restrict__ BT,
                                                   float* __restrict__ P) {
    __shared__ __align__(16) __bf16 Asm[128][BK];
    __shared__ __align__(16) __bf16 Bsm[128][BK];

    const int t = threadIdx.x;
    const int lane = t & 63;
    const int w = t >> 6;
    const int wrow = w >> 1;      // 0..1
    const int wcol = w & 1;       // 0..1
    const int row0 = blockIdx.y * 128;
    const int col0 = blockIdx.x * 128;

    const int sm = t >> 2;        // staging row 0..63 (round 2 adds 64)
    const int sc = (t & 3) * 8;   // staging k-offset

    f32x4 acc[4][4];
#pragma unroll
    for (int i = 0; i < 4; ++i)
#pragma unroll
        for (int j = 0; j < 4; ++j) acc[i][j] = (f32x4){0.f, 0.f, 0.f, 0.f};

    __bf16* asm0 = (__bf16*)Asm;
    __bf16* bsm0 = (__bf16*)Bsm;

    // prologue staging, k0 = 0
#pragma unroll
    for (int r = 0; r < 2; ++r) {
        stage16(A  + (size_t)(row0 + sm + r * 64) * GK + sc, asm0 + r * 2048 + t * 8);
        stage16(BT + (size_t)(col0 + sm + r * 64) * GK + sc, bsm0 + r * 2048 + t * 8);
    }

    const int mb = wrow * 64 + (lane & 15);
    const int nb = wcol * 64 + (lane & 15);
    const int kq = (lane >> 4) * 8;

    for (int kt = 0; kt < GK / BK; ++kt) {
        __syncthreads();   // staged tile visible

        bf16x8 af[4], bfr[4];
#pragma unroll
        for (int i = 0; i < 4; ++i) af[i]  = *(const bf16x8*)&Asm[mb + i * 16][kq];
#pragma unroll
        for (int j = 0; j < 4; ++j) bfr[j] = *(const bf16x8*)&Bsm[nb + j * 16][kq];

        __syncthreads();   // all reads landed; safe to overwrite

        if (kt + 1 < GK / BK) {
            int k0 = (kt + 1) * BK;
#pragma unroll
            for (int r = 0; r < 2; ++r) {
                stage16(A  + (size_t)(row0 + sm + r * 64) * GK + k0 + sc, asm0 + r * 2048 + t * 8);
                stage16(BT + (size_t)(col0 + sm + r * 64) * GK + k0 + sc, bsm0 + r * 2048 + t * 8);
            }
        }

#pragma unroll
        for (int i = 0; i < 4; ++i)
#pragma unroll
            for (int j = 0; j < 4; ++j)
                acc[i][j] = __builtin_amdgcn_mfma_f32_16x16x32_bf16(af[i], bfr[j], acc[i][j], 0, 0, 0);
    }

    // epilogue: C/D layout col=lane&15, row=(lane>>4)*4+reg
    const int colc = lane & 15;
    const int rq4 = (lane >> 4) * 4;
#pragma unroll
    for (int i = 0; i < 4; ++i) {
        int gr0 = row0 + wrow * 64 + i * 16 + rq4;
#pragma unroll
        for (int j = 0; j < 4; ++j) {
            int gc = col0 + wcol * 64 + j * 16 + colc;
#pragma unroll
            for (int r = 0; r < 4; ++r)
                P[(size_t)(gr0 + r) * OUT_F + gc] = acc[i][j][r];
        }
    }
}

// ---------------- row-norm of agg = S.X + noise (bf16 gather, fp32 accum) ----------------

__global__ void __launch_bounds__(192) k_norm(const __bf16* __restrict__ Abf,
                                              const int* __restrict__ offsets,
                                              const int* __restrict__ edge_src,
                                              float* __restrict__ rnorm) {
    __shared__ int nbuf[64];
    __shared__ float red[3];
    const int node = blockIdx.x;
    const int t = threadIdx.x;
    const int beg = offsets[node];
    const int end = offsets[node + 1];

    float acc[8] = {0.f, 0.f, 0.f, 0.f, 0.f, 0.f, 0.f, 0.f};
    if (t < NCHUNK) {
        bf16x8 v = *(const bf16x8*)(Abf + (size_t)(10000 + node) * GK + t * 8);
#pragma unroll
        for (int j = 0; j < 8; ++j) acc[j] = (float)v[j];
    }

    for (int cb = beg; cb < end; cb += 64) {
        int cnt = min(64, end - cb);
        __syncthreads();
        if (t < cnt) nbuf[t] = edge_src[cb + t];
        __syncthreads();
        for (int kk = 0; kk < cnt; ++kk) {
            if (t < NCHUNK) {
                bf16x8 v = *(const bf16x8*)(Abf + (size_t)nbuf[kk] * GK + t * 8);
#pragma unroll
                for (int j = 0; j < 8; ++j) acc[j] += (float)v[j];
            }
        }
    }

    float ss = 0.f;
#pragma unroll
    for (int j = 0; j < 8; ++j) ss += acc[j] * acc[j];
    for (int off = 32; off > 0; off >>= 1) ss += __shfl_down(ss, off, 64);
    if ((t & 63) == 0) red[t >> 6] = ss;
    __syncthreads();
    if (t == 0)
        rnorm[node] = 1.0f / fmaxf(sqrtf(red[0] + red[1] + red[2]), 1e-12f);
}

// ---------------- 256-dim aggregate of P + scale + bias ----------------

__global__ void __launch_bounds__(256) k_out(const float* __restrict__ P,
                                             const int* __restrict__ offsets,
                                             const int* __restrict__ edge_src,
                                             const float* __restrict__ rnorm,
                                             const float* __restrict__ bias,
                                             float* __restrict__ out) {
    __shared__ int nbuf[64];
    const int node = blockIdx.x;
    const int t = threadIdx.x;
    const int beg = offsets[node];
    const int end = offsets[node + 1];

    float acc = P[(size_t)(10000 + node) * OUT_F + t];   // noise @ W

    for (int cb = beg; cb < end; cb += 64) {
        int cnt = min(64, end - cb);
        __syncthreads();
        if (t < cnt) nbuf[t] = edge_src[cb + t];
        __syncthreads();
        for (int kk = 0; kk < cnt; ++kk)
            acc += P[(size_t)nbuf[kk] * OUT_F + t];
    }

    out[(size_t)node * OUT_F + t] = acc * rnorm[node] + bias[t];
}

// ---------------- launch ----------------

extern "C" void kernel_launch(void* const* d_in, const int* in_sizes, int n_in,
                              void* d_out, int out_size, void* d_ws, size_t ws_size,
                              hipStream_t stream) {
    const float* feat  = (const float*)d_in[0];
    const int*   edges = (const int*)d_in[1];
    const float* W     = (const float*)d_in[2];
    const float* bias  = (const float*)d_in[3];
    const float* noise = (const float*)d_in[4];
    float* out = (float*)d_out;

    char* ws = (char*)d_ws;
    size_t off = 0;
    auto carve = [&](size_t bytes) {
        void* p = ws + off;
        off = (off + bytes + 255) & ~(size_t)255;
        return p;
    };
    __bf16* Abf     = (__bf16*)carve((size_t)GM * GK * sizeof(__bf16));
    __bf16* WbfT    = (__bf16*)carve((size_t)OUT_F * GK * sizeof(__bf16));
    float*  P       = (float*)carve((size_t)GM * OUT_F * sizeof(float));
    float*  rnorm   = (float*)carve((size_t)N_NODES * sizeof(float));
    int*    counts  = (int*)carve((size_t)(N_NODES + 1) * sizeof(int));
    int*    offsets = (int*)carve((size_t)(N_NODES + 1) * sizeof(int));
    int*    cursor  = (int*)carve((size_t)(N_NODES + 1) * sizeof(int));
    int*    edge_src= (int*)carve((size_t)N_EDGES * sizeof(int));
    (void)ws_size;

    const int TB = 256;
    k_zero<<<(N_NODES + 1 + TB - 1) / TB, TB, 0, stream>>>(counts, N_NODES + 1);
    k_hist<<<(N_EDGES + TB - 1) / TB, TB, 0, stream>>>(edges, counts);
    k_scan<<<1, 1024, 0, stream>>>(counts, offsets);
    k_copy<<<(N_NODES + TB - 1) / TB, TB, 0, stream>>>(offsets, cursor, N_NODES);
    k_fill<<<(N_EDGES + TB - 1) / TB, TB, 0, stream>>>(edges, cursor, edge_src);

    k_convA<<<((size_t)GM * NCHUNK + TB - 1) / TB, TB, 0, stream>>>(feat, noise, Abf);
    k_convW<<<(OUT_F * GK + TB - 1) / TB, TB, 0, stream>>>(W, WbfT);

    dim3 ggrid(1, GM / 128);               // N=256 -> 2 col tiles
    ggrid.x = OUT_F / 128;
    k_mfma_gemm<<<ggrid, 256, 0, stream>>>(Abf, WbfT, P);

    k_norm<<<N_NODES, 192, 0, stream>>>(Abf, offsets, edge_src, rnorm);
    k_out<<<N_NODES, 256, 0, stream>>>(P, offsets, edge_src, rnorm, bias, out);
}

// Round 3
// 238.587 us; speedup vs baseline: 2.1840x; 1.2505x over previous
//
#include <hip/hip_runtime.h>
#include <math.h>

#define N_NODES 10000
#define N_EDGES 50000
#define IN_F    1433
#define OUT_F   256
#define GK      1440          // padded K: multiple of 32, rows 16B-aligned
#define NCHUNK  180           // GK/8
#define GM2     10112         // 79*128: agg rows padded to GEMM M tiles

typedef __bf16 bf16x8 __attribute__((ext_vector_type(8)));
typedef float  f32x4  __attribute__((ext_vector_type(4)));

typedef __attribute__((address_space(3))) unsigned int lds_u32;
typedef __attribute__((address_space(1))) unsigned int glb_u32;

__device__ __forceinline__ void stage16(const void* g, void* l) {
    __builtin_amdgcn_global_load_lds((glb_u32*)g, (lds_u32*)l, 16, 0, 0);
}

// ---------------- CSR build ----------------

__global__ void k_zero(int* __restrict__ counts, int n) {
    int i = blockIdx.x * blockDim.x + threadIdx.x;
    if (i < n) counts[i] = 0;
}

__global__ void k_hist(const int* __restrict__ edges, int* __restrict__ counts) {
    int e = blockIdx.x * blockDim.x + threadIdx.x;
    if (e < N_EDGES) {
        int dst = edges[2 * e];
        int src = edges[2 * e + 1];
        if (src < N_NODES) atomicAdd(&counts[dst], 1);
    }
}

// shuffle-based single-block scan: 3 syncs per 1024-chunk
__global__ void __launch_bounds__(1024) k_scan(const int* __restrict__ counts,
                                               int* __restrict__ offsets,
                                               int* __restrict__ cursor) {
    __shared__ int wsum[16];
    __shared__ int carry_s;
    const int t = threadIdx.x, lane = t & 63, wid = t >> 6;
    if (t == 0) carry_s = 0;
    __syncthreads();
    for (int base = 0; base < N_NODES; base += 1024) {
        int i = base + t;
        int v = (i < N_NODES) ? counts[i] : 0;
        int s = v;
#pragma unroll
        for (int off = 1; off < 64; off <<= 1) {
            int u = __shfl_up(s, off, 64);
            if (lane >= off) s += u;
        }
        if (lane == 63) wsum[wid] = s;
        __syncthreads();
        if (t == 0) {
            int run = carry_s;
#pragma unroll
            for (int w2 = 0; w2 < 16; ++w2) { int tmp = wsum[w2]; wsum[w2] = run; run += tmp; }
            carry_s = run;
        }
        __syncthreads();
        int excl = wsum[wid] + s - v;
        if (i < N_NODES) { offsets[i] = excl; cursor[i] = excl; }
        __syncthreads();
    }
    if (t == 0) offsets[N_NODES] = carry_s;
}

__global__ void k_fill(const int* __restrict__ edges, int* __restrict__ cursor,
                       int* __restrict__ edge_src) {
    int e = blockIdx.x * blockDim.x + threadIdx.x;
    if (e < N_EDGES) {
        int dst = edges[2 * e];
        int src = edges[2 * e + 1];
        if (src < N_NODES) {
            int pos = atomicAdd(&cursor[dst], 1);
            edge_src[pos] = src;
        }
    }
}

// ---------------- fp32 -> bf16 convert: flat float4 reads, scattered 2B stores ----
// Xbf rows 0..9999 = X, rows 10000..19999 = noise; pad cols zeroed by k_prep

#define NQUADS ((N_NODES * IN_F) / 4)   // 3582500, exact

__global__ void k_conv(const float* __restrict__ X, const float* __restrict__ noise,
                       __bf16* __restrict__ Xbf) {
    int i = blockIdx.x * blockDim.x + threadIdx.x;
    if (i >= NQUADS) return;
    const float* src = blockIdx.y ? noise : X;
    const int rbase = blockIdx.y ? N_NODES : 0;
    float4 v = ((const float4*)src)[i];
    unsigned elem = 4u * (unsigned)i;
    unsigned row = elem / 1433u;
    unsigned col0 = elem - row * 1433u;
    float vv[4] = {v.x, v.y, v.z, v.w};
#pragma unroll
    for (int j = 0; j < 4; ++j) {
        unsigned c = col0 + j, r = row;
        if (c >= 1433u) { c -= 1433u; r += 1u; }
        Xbf[(size_t)(rbase + r) * GK + c] = (__bf16)vv[j];
    }
}

// ---------------- prep: W^T (bf16, zero-padded K) + zero all pad regions ------

#define PREP_W  (OUT_F * GK)            // 368640
#define PREP_XP (2 * N_NODES * (GK - IN_F))  // 140000
#define PREP_AP ((GM2 - N_NODES) * GK)  // 161280

__global__ void k_prep(const float* __restrict__ W, __bf16* __restrict__ BT,
                       __bf16* __restrict__ Xbf, __bf16* __restrict__ aggbf) {
    int i = blockIdx.x * blockDim.x + threadIdx.x;
    if (i < PREP_W) {
        int n = i / GK, k = i % GK;
        BT[i] = (__bf16)((k < IN_F) ? W[(size_t)k * OUT_F + n] : 0.0f);
    } else if (i < PREP_W + PREP_XP) {
        int j = i - PREP_W;
        int r = j / (GK - IN_F), c = IN_F + j % (GK - IN_F);
        Xbf[(size_t)r * GK + c] = (__bf16)0.0f;
    } else if (i < PREP_W + PREP_XP + PREP_AP) {
        int j = i - (PREP_W + PREP_XP);
        aggbf[(size_t)N_NODES * GK + j] = (__bf16)0.0f;
    }
}

// ---------------- aggregate (bf16 gather, fp32 accum) + fused norm -------------
// agg[i] = noise[i] + sum_{src in N(i)} X[src];  rnorm[i] = 1/max(||agg||,1e-12)

__global__ void __launch_bounds__(192) k_agg(const __bf16* __restrict__ Xbf,
                                             const int* __restrict__ offsets,
                                             const int* __restrict__ edge_src,
                                             __bf16* __restrict__ aggbf,
                                             float* __restrict__ rnorm) {
    __shared__ int nbuf[64];
    __shared__ float red[3];
    const int node = blockIdx.x;
    const int t = threadIdx.x;
    const int beg = offsets[node], end = offsets[node + 1];

    float acc[8] = {0.f, 0.f, 0.f, 0.f, 0.f, 0.f, 0.f, 0.f};
    if (t < NCHUNK) {
        bf16x8 v = *(const bf16x8*)(Xbf + (size_t)(N_NODES + node) * GK + t * 8);
#pragma unroll
        for (int j = 0; j < 8; ++j) acc[j] = (float)v[j];
    }

    for (int cb = beg; cb < end; cb += 64) {
        int cnt = min(64, end - cb);
        __syncthreads();
        if (t < cnt) nbuf[t] = edge_src[cb + t];
        __syncthreads();
        for (int kk = 0; kk < cnt; ++kk) {
            if (t < NCHUNK) {
                bf16x8 v = *(const bf16x8*)(Xbf + (size_t)nbuf[kk] * GK + t * 8);
#pragma unroll
                for (int j = 0; j < 8; ++j) acc[j] += (float)v[j];
            }
        }
    }

    float ss = 0.f;
    if (t < NCHUNK) {
        bf16x8 o;
#pragma unroll
        for (int j = 0; j < 8; ++j) { o[j] = (__bf16)acc[j]; ss += acc[j] * acc[j]; }
        *(bf16x8*)(aggbf + (size_t)node * GK + t * 8) = o;
    }
    for (int off = 32; off > 0; off >>= 1) ss += __shfl_down(ss, off, 64);
    if ((t & 63) == 0) red[t >> 6] = ss;
    __syncthreads();
    if (t == 0)
        rnorm[node] = 1.0f / fmaxf(sqrtf(red[0] + red[1] + red[2]), 1e-12f);
}

// ---------------- bf16 MFMA GEMM: out = (aggbf @ WbfT^T) * rnorm + bias --------
// 128x128 tile, BK=32, 256 thr = 4 waves, each wave 64x64 (4x4 of 16x16x32)

#define BK 32

__global__ void __launch_bounds__(256) k_gemm(const __bf16* __restrict__ A,
                                              const __bf16* __restrict__ BT,
                                              const float* __restrict__ rnorm,
                                              const float* __restrict__ bias,
                                              float* __restrict__ out) {
    __shared__ __align__(16) __bf16 Asm[128][BK];
    __shared__ __align__(16) __bf16 Bsm[128][BK];

    const int t = threadIdx.x;
    const int lane = t & 63;
    const int w = t >> 6;
    const int wrow = w >> 1;
    const int wcol = w & 1;
    const int row0 = blockIdx.y * 128;
    const int col0 = blockIdx.x * 128;

    const int sm = t >> 2;
    const int sc = (t & 3) * 8;

    f32x4 acc[4][4];
#pragma unroll
    for (int i = 0; i < 4; ++i)
#pragma unroll
        for (int j = 0; j < 4; ++j) acc[i][j] = (f32x4){0.f, 0.f, 0.f, 0.f};

    __bf16* asm0 = (__bf16*)Asm;
    __bf16* bsm0 = (__bf16*)Bsm;

#pragma unroll
    for (int r = 0; r < 2; ++r) {
        stage16(A  + (size_t)(row0 + sm + r * 64) * GK + sc, asm0 + r * 2048 + t * 8);
        stage16(BT + (size_t)(col0 + sm + r * 64) * GK + sc, bsm0 + r * 2048 + t * 8);
    }

    const int mb = wrow * 64 + (lane & 15);
    const int nb = wcol * 64 + (lane & 15);
    const int kq = (lane >> 4) * 8;

    for (int kt = 0; kt < GK / BK; ++kt) {
        __syncthreads();

        bf16x8 af[4], bfr[4];
#pragma unroll
        for (int i = 0; i < 4; ++i) af[i]  = *(const bf16x8*)&Asm[mb + i * 16][kq];
#pragma unroll
        for (int j = 0; j < 4; ++j) bfr[j] = *(const bf16x8*)&Bsm[nb + j * 16][kq];

        __syncthreads();

        if (kt + 1 < GK / BK) {
            int k0 = (kt + 1) * BK;
#pragma unroll
            for (int r = 0; r < 2; ++r) {
                stage16(A  + (size_t)(row0 + sm + r * 64) * GK + k0 + sc, asm0 + r * 2048 + t * 8);
                stage16(BT + (size_t)(col0 + sm + r * 64) * GK + k0 + sc, bsm0 + r * 2048 + t * 8);
            }
        }

#pragma unroll
        for (int i = 0; i < 4; ++i)
#pragma unroll
            for (int j = 0; j < 4; ++j)
                acc[i][j] = __builtin_amdgcn_mfma_f32_16x16x32_bf16(af[i], bfr[j], acc[i][j], 0, 0, 0);
    }

    // epilogue: C/D layout col=lane&15, row=(lane>>4)*4+reg; fuse rnorm + bias
    const int colc = lane & 15;
    const int rq4 = (lane >> 4) * 4;
#pragma unroll
    for (int i = 0; i < 4; ++i) {
        int gr0 = row0 + wrow * 64 + i * 16 + rq4;
#pragma unroll
        for (int r = 0; r < 4; ++r) {
            int gr = gr0 + r;
            if (gr < N_NODES) {
                float rn = rnorm[gr];
#pragma unroll
                for (int j = 0; j < 4; ++j) {
                    int gc = col0 + wcol * 64 + j * 16 + colc;
                    out[(size_t)gr * OUT_F + gc] = acc[i][j][r] * rn + bias[gc];
                }
            }
        }
    }
}

// ---------------- launch ----------------

extern "C" void kernel_launch(void* const* d_in, const int* in_sizes, int n_in,
                              void* d_out, int out_size, void* d_ws, size_t ws_size,
                              hipStream_t stream) {
    const float* feat  = (const float*)d_in[0];
    const int*   edges = (const int*)d_in[1];
    const float* W     = (const float*)d_in[2];
    const float* bias  = (const float*)d_in[3];
    const float* noise = (const float*)d_in[4];
    float* out = (float*)d_out;

    char* ws = (char*)d_ws;
    size_t off = 0;
    auto carve = [&](size_t bytes) {
        void* p = ws + off;
        off = (off + bytes + 255) & ~(size_t)255;
        return p;
    };
    __bf16* Xbf     = (__bf16*)carve((size_t)2 * N_NODES * GK * sizeof(__bf16));
    __bf16* aggbf   = (__bf16*)carve((size_t)GM2 * GK * sizeof(__bf16));
    __bf16* WbfT    = (__bf16*)carve((size_t)OUT_F * GK * sizeof(__bf16));
    float*  rnorm   = (float*)carve((size_t)N_NODES * sizeof(float));
    int*    counts  = (int*)carve((size_t)(N_NODES + 1) * sizeof(int));
    int*    offsets = (int*)carve((size_t)(N_NODES + 1) * sizeof(int));
    int*    cursor  = (int*)carve((size_t)(N_NODES + 1) * sizeof(int));
    int*    edge_src= (int*)carve((size_t)N_EDGES * sizeof(int));
    (void)ws_size;

    const int TB = 256;
    k_zero<<<(N_NODES + 1 + TB - 1) / TB, TB, 0, stream>>>(counts, N_NODES + 1);
    k_hist<<<(N_EDGES + TB - 1) / TB, TB, 0, stream>>>(edges, counts);
    k_scan<<<1, 1024, 0, stream>>>(counts, offsets, cursor);
    k_fill<<<(N_EDGES + TB - 1) / TB, TB, 0, stream>>>(edges, cursor, edge_src);

    dim3 cgrid((NQUADS + TB - 1) / TB, 2);
    k_conv<<<cgrid, TB, 0, stream>>>(feat, noise, Xbf);

    int prep_total = PREP_W + PREP_XP + PREP_AP;
    k_prep<<<(prep_total + TB - 1) / TB, TB, 0, stream>>>(W, WbfT, Xbf, aggbf);

    k_agg<<<N_NODES, 192, 0, stream>>>(Xbf, offsets, edge_src, aggbf, rnorm);

    dim3 ggrid(OUT_F / 128, GM2 / 128);
    k_gemm<<<ggrid, 256, 0, stream>>>(aggbf, WbfT, rnorm, bias, out);
}